// Round 1
// baseline (117.209 us; speedup 1.0000x reference)
//
#include <hip/hip_runtime.h>

// PhraseAveragePretrainedEmbedding — prefix-sum formulation, v8.
// out[b,t,:] = (P[e]-P[a]) / max(e-a,1); spans contiguous by the XOR-mask
// identity (a=min(lo,hi+1), e=max(lo,hi+1)).
//
// v8: single-gather restructure. v7's buildP re-gathered the same 19.7 MB
// of W rows csum had already gathered, plus an O(c) serial csum-prefix per
// block. Now:
//   csumP_kernel : ONE gather -> base-free local-prefix P + chunk totals
//   base_kernel  : exclusive scan of chunk totals -> base[b][NC+1][D]
//                  (1.2 MB, L2-resident; embarrassingly parallel per entry)
//   out_kernel   : P_full[s] = P_local[s] + base[s>>4]  (2 extra tiny-
//                  footprint L2 loads per row, latency-hidden)
// CHUNK 32->16 doubles the gather grid (1024 blocks = 4/CU, 20 waves/CU)
// for better L3-gather latency hiding. leaves_kernel: one 64-entry wave
// scan (2 syncthreads) instead of 8 ballot rounds (24 syncthreads).

#define BB 8
#define TT 4095
#define SS 2048
#define DD 300
#define D4 75            // DD/4
#define PADIDX 1
#define CHUNK 16
#define NC (SS / CHUNK)  // 128
#define NTB 320

typedef float f4 __attribute__((ext_vector_type(4)));

__global__ __launch_bounds__(512) void leaves_kernel(const int* __restrict__ x,
                                                     const int* __restrict__ idx,
                                                     int* __restrict__ leaves) {
    int b = blockIdx.x, tid = threadIdx.x;
    int lane = tid & 63, w = tid >> 6;  // 8 waves
    __shared__ int wcnt[64];            // per-(k,w) leaf counts, (k,w) in t-order
    __shared__ int stotal;
    const int* xb = x + b * TT;
    const int2* ib2 = (const int2*)(idx + b * 2 * TT);

    int xv[8];
    bool lf8[8];
    unsigned long long bal[8];
#pragma unroll
    for (int k = 0; k < 8; ++k) {
        int t = tid + k * 512;
        xv[k] = 0;
        lf8[k] = false;
        if (t < TT) {
            xv[k] = xb[t];
            int2 pr = ib2[t];
            lf8[k] = (pr.x == pr.y) && (xv[k] != PADIDX);
        }
    }
#pragma unroll
    for (int k = 0; k < 8; ++k) {
        bal[k] = __ballot(lf8[k]);
        if (lane == 0) wcnt[k * 8 + w] = __popcll(bal[k]);
    }
    __syncthreads();
    if (w == 0) {  // wave 0: exclusive scan of the 64 (k,w) counts
        int v = wcnt[lane];
        int s = v;
#pragma unroll
        for (int d = 1; d < 64; d <<= 1) {
            int t2 = __shfl_up(s, d);
            if (lane >= d) s += t2;
        }
        wcnt[lane] = s - v;  // exclusive prefix
        if (lane == 63) stotal = s;
    }
    __syncthreads();
#pragma unroll
    for (int k = 0; k < 8; ++k) {
        int pos = wcnt[k * 8 + w] + __popcll(bal[k] & ((1ull << lane) - 1ull));
        if (lf8[k] && pos < SS) leaves[b * SS + pos] = xv[k];
    }
    for (int i = stotal + tid; i < SS; i += 512) leaves[b * SS + i] = PADIDX;
}

// 1024 blocks: batch = blk & 7 (XCD swizzle), chunk = blk >> 3 (16 rows).
// 320 threads = 4 groups x 80 lanes (75 active f4 lanes). Single gather into
// LDS, then base-free local prefix written to P + chunk total to csum.
__global__ __launch_bounds__(NTB) void csumP_kernel(const int* __restrict__ leaves,
                                                    const float* __restrict__ W,
                                                    float* __restrict__ csum,
                                                    float* __restrict__ P) {
    int blk = blockIdx.x;
    int b = blk & 7, c = blk >> 3;
    int tid = threadIdx.x;
    int g = tid / 80, j = tid - g * 80;
    __shared__ int lf[CHUNK];
    __shared__ f4 sw[CHUNK][D4];  // 19200 B
    if (tid < CHUNK) lf[tid] = leaves[b * SS + c * CHUNK + tid];
    __syncthreads();
    const f4* W4 = (const f4*)W;
    if (j < D4) {
#pragma unroll
        for (int i = 0; i < 4; ++i)
            sw[g * 4 + i][j] = W4[(size_t)lf[g * 4 + i] * D4 + j];
    }
    __syncthreads();
    if (j >= D4) return;

    f4* P4 = (f4*)P + (size_t)b * (SS + 1) * D4;
    int s0 = c * CHUNK;
    f4 run = (f4)0.f;
    // catch up to this group's first row (<=12 LDS reads)
    for (int k = 0; k < g * 4; ++k) run += sw[k][j];
#pragma unroll
    for (int i = 0; i < 4; ++i) {
        int row = g * 4 + i;
        P4[(size_t)(s0 + row) * D4 + j] = run;  // local (base-free) prefix
        run += sw[row][j];
    }
    if (g == 3) {
        ((f4*)csum)[(b * NC + c) * D4 + j] = run;       // chunk total
        if (c == NC - 1) P4[(size_t)SS * D4 + j] = (f4)0.f;  // P_local[SS]=0
    }
}

// 1032 blocks: batch = blk & 7, cc = blk >> 3 in [0, NC]. Each block sums
// csum rows [0, cc) -> exclusive base. 4 groups stride the cc range, LDS
// reduce. Total reads ~80 MB of a 1.2 MB L2-resident buffer.
__global__ __launch_bounds__(NTB) void base_kernel(const float* __restrict__ csum,
                                                   float* __restrict__ base) {
    int blk = blockIdx.x;
    int b = blk & 7, cc = blk >> 3;
    int tid = threadIdx.x;
    int g = tid / 80, j = tid - g * 80;
    __shared__ f4 part[4][D4];
    const f4* csum4 = (const f4*)csum;
    f4 acc = (f4)0.f;
    if (j < D4) {
        for (int i = g; i < cc; i += 4) acc += csum4[(b * NC + i) * D4 + j];
        part[g][j] = acc;
    }
    __syncthreads();
    if (g == 0 && j < D4) {
        f4 s = part[0][j] + part[1][j] + part[2][j] + part[3][j];
        ((f4*)base)[(b * (NC + 1) + cc) * D4 + j] = s;
    }
}

// 2048 blocks: batch = blk & 7 (XCD swizzle), row-group = blk >> 3 (16 rows).
// 320 threads = 4 row-slots x 80 lanes. P_full[s] = P_local[s] + base[s>>4].
__global__ __launch_bounds__(NTB) void out_kernel(const int* __restrict__ idx,
                                                  const float* __restrict__ P,
                                                  const float* __restrict__ base,
                                                  float* __restrict__ out) {
    int tid = threadIdx.x;
    int r = tid / 80, j = tid - r * 80;
    int b = blockIdx.x & 7;
    int g = blockIdx.x >> 3;
    const f4* P4 = (const f4*)P + (size_t)b * (SS + 1) * D4;
    const f4* B4 = (const f4*)base + (size_t)b * (NC + 1) * D4;
    f4* out4 = (f4*)out;
    const int2* ixb = (const int2*)(idx + 2 * b * TT);
#pragma unroll
    for (int it = 0; it < 4; ++it) {
        int lr = g * 16 + r + it * 4;
        if (lr >= TT || j >= D4) continue;
        int2 pr = ixb[lr];
        int u = pr.y + 1;
        int a = min(pr.x, u), e = max(pr.x, u);
        a = max(0, min(a, SS));
        e = max(0, min(e, SS));
        int cnt = e - a;
        float inv = 1.0f / (float)(cnt > 0 ? cnt : 1);
        f4 ve = P4[(size_t)e * D4 + j] + B4[(e >> 4) * D4 + j];
        f4 va = P4[(size_t)a * D4 + j] + B4[(a >> 4) * D4 + j];
        f4 o = (ve - va) * inv;
        __builtin_nontemporal_store(o, &out4[((size_t)b * TT + lr) * D4 + j]);
    }
}

extern "C" void kernel_launch(void* const* d_in, const int* in_sizes, int n_in,
                              void* d_out, int out_size, void* d_ws, size_t ws_size,
                              hipStream_t stream) {
    const int* x = (const int*)d_in[0];
    const int* idx = (const int*)d_in[1];
    const float* W = (const float*)d_in[2];
    float* out = (float*)d_out;

    char* ws = (char*)d_ws;
    int* leaves = (int*)ws;                       // B*SS ints        = 64 KiB
    float* csum = (float*)(ws + 65536);           // B*NC*DD f32      = 1.2 MiB
    float* base = (float*)(ws + 65536 + 1228800); // B*(NC+1)*DD f32  = 1.2 MiB
    float* P = (float*)(ws + 2532736);            // B*(SS+1)*DD f32  = 18.8 MiB

    leaves_kernel<<<BB, 512, 0, stream>>>(x, idx, leaves);
    csumP_kernel<<<BB * NC, NTB, 0, stream>>>(leaves, W, csum, P);
    base_kernel<<<BB * (NC + 1), NTB, 0, stream>>>(csum, base);
    out_kernel<<<(BB * TT + 15) / 16, NTB, 0, stream>>>(idx, P, base, out);
}